// Round 1
// baseline (335.733 us; speedup 1.0000x reference)
//
#include <hip/hip_runtime.h>

// Multi-Scale Deformable Attention, fused single kernel.
// BS=2, NQ=32768, C=128, NH=1, NL=2, NP=8, NV=40960
// shapes: level0 = 128x256 (start 0), level1 = 64x128 (start 32768)

#define QB 64  // queries per block

__global__ __launch_bounds__(256) void msda_fused_kernel(
    const float* __restrict__ query,
    const float* __restrict__ value,
    const float* __restrict__ qloc,
    const float* __restrict__ Woff,
    const float* __restrict__ boff,
    const float* __restrict__ Wattn,
    const float* __restrict__ battn,
    const float* __restrict__ Wout,
    const float* __restrict__ bout,
    float* __restrict__ out)
{
    __shared__ float q_tile[QB * 128];   // 32 KB; reused as acc tile after logits
    __shared__ float coords[QB * 32];    // 8 KB: [q][ (l*8+p)*2 + d ]
    __shared__ float aws[QB * 16];       // 4 KB: [q][ l*8+p ]

    const int tid = threadIdx.x;
    const int r0  = blockIdx.x * QB;     // flat row index = b*32768 + q

    // ---- phase 1: stage 64x128 query tile into LDS (coalesced float4) ----
    {
        const float4* src = (const float4*)query + (size_t)r0 * 32;
        float4* dst = (float4*)q_tile;
        #pragma unroll
        for (int i = 0; i < 8; ++i)
            dst[tid + i * 256] = src[tid + i * 256];
    }
    __syncthreads();

    // ---- phase 2: offset logits -> sample coordinates ----
    // thread t: column jo = t&31 of W_off, queries qb..qb+7 (qb = (t>>5)*8)
    {
        const int jo = tid & 31;
        const int qb = (tid >> 5) * 8;
        float s[8];
        #pragma unroll
        for (int k = 0; k < 8; ++k) s[k] = 0.f;
        for (int c4 = 0; c4 < 32; ++c4) {
            const float w0 = Woff[(c4 * 4 + 0) * 32 + jo];
            const float w1 = Woff[(c4 * 4 + 1) * 32 + jo];
            const float w2 = Woff[(c4 * 4 + 2) * 32 + jo];
            const float w3 = Woff[(c4 * 4 + 3) * 32 + jo];
            #pragma unroll
            for (int k = 0; k < 8; ++k) {
                const float4 q4 = *(const float4*)&q_tile[(qb + k) * 128 + c4 * 4];
                s[k] += q4.x * w0 + q4.y * w1 + q4.z * w2 + q4.w * w3;
            }
        }
        // jo = (l*8+p)*2 + d  with l = jo>>4, d = jo&1
        const int l = jo >> 4;
        const int d = jo & 1;
        // offset normalizer [W,H]: x = ql_x*W + off_x - 0.5 ; y = ql_y*H + off_y - 0.5
        const float scale = (d == 0) ? (l == 0 ? 256.f : 128.f)
                                     : (l == 0 ? 128.f : 64.f);
        const float bo = boff[jo];
        #pragma unroll
        for (int k = 0; k < 8; ++k) {
            const int row = r0 + qb + k;
            const float ql = qloc[row * 4 + l * 2 + d];
            coords[(qb + k) * 32 + jo] = ql * scale + (s[k] + bo) - 0.5f;
        }
    }

    // ---- phase 3: attention logits ----
    {
        const int ja = tid & 15;
        const int qb = (tid >> 4) * 4;
        float s[4] = {0.f, 0.f, 0.f, 0.f};
        for (int c4 = 0; c4 < 32; ++c4) {
            const float w0 = Wattn[(c4 * 4 + 0) * 16 + ja];
            const float w1 = Wattn[(c4 * 4 + 1) * 16 + ja];
            const float w2 = Wattn[(c4 * 4 + 2) * 16 + ja];
            const float w3 = Wattn[(c4 * 4 + 3) * 16 + ja];
            #pragma unroll
            for (int k = 0; k < 4; ++k) {
                const float4 q4 = *(const float4*)&q_tile[(qb + k) * 128 + c4 * 4];
                s[k] += q4.x * w0 + q4.y * w1 + q4.z * w2 + q4.w * w3;
            }
        }
        const float ba = battn[ja];
        #pragma unroll
        for (int k = 0; k < 4; ++k)
            aws[(qb + k) * 16 + ja] = s[k] + ba;
    }
    __syncthreads();

    // ---- softmax over the 16 (level,point) weights, one thread per query ----
    if (tid < QB) {
        float* a = &aws[tid * 16];
        float m = a[0];
        #pragma unroll
        for (int j = 1; j < 16; ++j) m = fmaxf(m, a[j]);
        float sum = 0.f;
        #pragma unroll
        for (int j = 0; j < 16; ++j) {
            const float e = __expf(a[j] - m);
            a[j] = e;
            sum += e;
        }
        const float r = 1.f / sum;
        #pragma unroll
        for (int j = 0; j < 16; ++j) a[j] *= r;
    }
    __syncthreads();

    // ---- gather: half-wave (32 lanes) per query, float4 of channels per lane ----
    {
        const int grp  = tid >> 5;   // 0..7
        const int lane = tid & 31;   // channel group: ch = lane*4..lane*4+3
        const float4* vb = (const float4*)value + (size_t)(r0 >> 15) * (40960 * 32);
        #pragma unroll 1
        for (int i = 0; i < 8; ++i) {
            const int q = grp * 8 + i;
            float ax = 0.f, ay = 0.f, az = 0.f, a_w = 0.f;
            #pragma unroll
            for (int l = 0; l < 2; ++l) {
                const int H = (l == 0) ? 128 : 64;
                const int W = (l == 0) ? 256 : 128;
                const int S = (l == 0) ? 0 : 32768;
                #pragma unroll
                for (int p = 0; p < 8; ++p) {
                    const float x   = coords[q * 32 + (l * 8 + p) * 2 + 0];
                    const float y   = coords[q * 32 + (l * 8 + p) * 2 + 1];
                    const float wgt = aws[q * 16 + l * 8 + p];
                    const float xf = floorf(x), yf = floorf(y);
                    const float lx = x - xf, ly = y - yf;
                    const int x0 = (int)xf, y0 = (int)yf;
                    const int x1 = x0 + 1, y1 = y0 + 1;
                    const float hx = 1.f - lx, hy = 1.f - ly;
                    float w00 = wgt * hx * hy;
                    float w10 = wgt * lx * hy;
                    float w01 = wgt * hx * ly;
                    float w11 = wgt * lx * ly;
                    // zero-padding outside the feature map
                    if (x0 < 0 || x0 >= W) { w00 = 0.f; w01 = 0.f; }
                    if (x1 < 0 || x1 >= W) { w10 = 0.f; w11 = 0.f; }
                    if (y0 < 0 || y0 >= H) { w00 = 0.f; w10 = 0.f; }
                    if (y1 < 0 || y1 >= H) { w01 = 0.f; w11 = 0.f; }
                    const int cx0 = min(max(x0, 0), W - 1);
                    const int cx1 = min(max(x1, 0), W - 1);
                    const int cy0 = min(max(y0, 0), H - 1);
                    const int cy1 = min(max(y1, 0), H - 1);
                    const float4 v00 = vb[(S + cy0 * W + cx0) * 32 + lane];
                    const float4 v10 = vb[(S + cy0 * W + cx1) * 32 + lane];
                    const float4 v01 = vb[(S + cy1 * W + cx0) * 32 + lane];
                    const float4 v11 = vb[(S + cy1 * W + cx1) * 32 + lane];
                    ax += w00 * v00.x + w10 * v10.x + w01 * v01.x + w11 * v11.x;
                    ay += w00 * v00.y + w10 * v10.y + w01 * v01.y + w11 * v11.y;
                    az += w00 * v00.z + w10 * v10.z + w01 * v01.z + w11 * v11.z;
                    a_w += w00 * v00.w + w10 * v10.w + w01 * v01.w + w11 * v11.w;
                }
            }
            // q_tile is free now (logits consumed it before the last barrier)
            ((float4*)q_tile)[q * 32 + lane] = make_float4(ax, ay, az, a_w);
        }
    }
    __syncthreads();

    // ---- output GEMM: out[64x128] = acc[64x128] @ Wout[128x128] + bout ----
    // thread t: 4 output cols co*4.., 8 queries qb..qb+7
    {
        const int co = tid & 31;
        const int qb = (tid >> 5) * 8;
        float4 o[8];
        #pragma unroll
        for (int k = 0; k < 8; ++k) o[k] = make_float4(0.f, 0.f, 0.f, 0.f);
        const float4* Wr = (const float4*)Wout;
        for (int ci = 0; ci < 128; ++ci) {
            const float4 w4 = Wr[ci * 32 + co];
            #pragma unroll
            for (int k = 0; k < 8; ++k) {
                const float a = q_tile[(qb + k) * 128 + ci];
                o[k].x += a * w4.x;
                o[k].y += a * w4.y;
                o[k].z += a * w4.z;
                o[k].w += a * w4.w;
            }
        }
        const float4 b4 = ((const float4*)bout)[co];
        float4* og = (float4*)out;
        #pragma unroll
        for (int k = 0; k < 8; ++k) {
            const int row = r0 + qb + k;
            float4 r = o[k];
            r.x += b4.x; r.y += b4.y; r.z += b4.z; r.w += b4.w;
            og[(size_t)row * 32 + co] = r;
        }
    }
}

extern "C" void kernel_launch(void* const* d_in, const int* in_sizes, int n_in,
                              void* d_out, int out_size, void* d_ws, size_t ws_size,
                              hipStream_t stream) {
    const float* query = (const float*)d_in[0];
    const float* value = (const float*)d_in[1];
    const float* qloc  = (const float*)d_in[2];
    // d_in[3] spatial_shapes, d_in[4] level_start_index: compile-time constants here
    const float* Woff  = (const float*)d_in[5];
    const float* boff  = (const float*)d_in[6];
    const float* Wattn = (const float*)d_in[7];
    const float* battn = (const float*)d_in[8];
    const float* Wout  = (const float*)d_in[9];
    const float* bout  = (const float*)d_in[10];
    float* out = (float*)d_out;

    dim3 grid(1024);   // 65536 rows / 64 per block
    dim3 block(256);
    hipLaunchKernelGGL(msda_fused_kernel, grid, block, 0, stream,
                       query, value, qloc, Woff, boff, Wattn, battn, Wout, bout, out);
}

// Round 2
// 281.107 us; speedup vs baseline: 1.1943x; 1.1943x over previous
//
#include <hip/hip_runtime.h>

// Multi-Scale Deformable Attention, split: gather kernel + in-place output GEMM.
// BS=2, NQ=32768, C=128, NH=1, NL=2, NP=8, NV=40960
// level0 = 128x256 (start 0), level1 = 64x128 (start 32768)

#define QB 32  // queries per block (gather kernel)

__global__ __launch_bounds__(256, 4) void msda_gather_kernel(
    const float* __restrict__ query,
    const float* __restrict__ value,
    const float* __restrict__ qloc,
    const float* __restrict__ Woff,
    const float* __restrict__ boff,
    const float* __restrict__ Wattn,
    const float* __restrict__ battn,
    float* __restrict__ acc_out)   // d_out used as acc buffer [65536 x 128]
{
    // 16 KB region: q_tile during logits, then (wo_w, wo_o) sample tables
    __shared__ __align__(16) char smem_u[QB * 128 * 4];
    __shared__ float coords[QB * 32];   // 4 KB: [q][p*2 + d]
    __shared__ float aws[QB * 16];      // 2 KB: [q][p]

    float*  q_tile = (float*)smem_u;
    float4* wo_w   = (float4*)smem_u;                  // 512 entries, 8 KB
    int4*   wo_o   = (int4*)(smem_u + QB * 16 * 16);   // 512 entries, 8 KB

    const int tid = threadIdx.x;
    const int r0  = blockIdx.x * QB;    // flat row = b*32768 + q

    // ---- phase 1: stage 32x128 query tile (1024 float4, coalesced) ----
    {
        const float4* src = (const float4*)query + (size_t)r0 * 32;
        float4* dst = (float4*)q_tile;
        #pragma unroll
        for (int i = 0; i < 4; ++i)
            dst[tid + i * 256] = src[tid + i * 256];
    }
    __syncthreads();

    // ---- phase 2: offset logits -> sample coordinates ----
    {
        const int jo = tid & 31;          // offset column 0..31
        const int qb = (tid >> 5) * 4;    // 8 groups x 4 queries
        float s[4] = {0.f, 0.f, 0.f, 0.f};
        for (int c4 = 0; c4 < 32; ++c4) {
            const float w0 = Woff[(c4 * 4 + 0) * 32 + jo];
            const float w1 = Woff[(c4 * 4 + 1) * 32 + jo];
            const float w2 = Woff[(c4 * 4 + 2) * 32 + jo];
            const float w3 = Woff[(c4 * 4 + 3) * 32 + jo];
            #pragma unroll
            for (int k = 0; k < 4; ++k) {
                const float4 q4 = *(const float4*)&q_tile[(qb + k) * 128 + c4 * 4];
                s[k] += q4.x * w0 + q4.y * w1 + q4.z * w2 + q4.w * w3;
            }
        }
        const int l = jo >> 4;
        const int d = jo & 1;
        const float scale = (d == 0) ? (l == 0 ? 256.f : 128.f)
                                     : (l == 0 ? 128.f : 64.f);
        const float bo = boff[jo];
        #pragma unroll
        for (int k = 0; k < 4; ++k) {
            const int row = r0 + qb + k;
            const float ql = qloc[row * 4 + l * 2 + d];
            coords[(qb + k) * 32 + jo] = ql * scale + (s[k] + bo) - 0.5f;
        }
    }

    // ---- phase 3: attention logits ----
    {
        const int ja = tid & 15;
        const int qb = (tid >> 4) * 2;    // 16 groups x 2 queries
        float s[2] = {0.f, 0.f};
        for (int c4 = 0; c4 < 32; ++c4) {
            const float w0 = Wattn[(c4 * 4 + 0) * 16 + ja];
            const float w1 = Wattn[(c4 * 4 + 1) * 16 + ja];
            const float w2 = Wattn[(c4 * 4 + 2) * 16 + ja];
            const float w3 = Wattn[(c4 * 4 + 3) * 16 + ja];
            #pragma unroll
            for (int k = 0; k < 2; ++k) {
                const float4 q4 = *(const float4*)&q_tile[(qb + k) * 128 + c4 * 4];
                s[k] += q4.x * w0 + q4.y * w1 + q4.z * w2 + q4.w * w3;
            }
        }
        const float ba = battn[ja];
        #pragma unroll
        for (int k = 0; k < 2; ++k)
            aws[(qb + k) * 16 + ja] = s[k] + ba;
    }
    __syncthreads();   // coords + attn logits ready; q_tile reads complete

    // ---- softmax over 16 weights per query ----
    if (tid < QB) {
        float* a = &aws[tid * 16];
        float m = a[0];
        #pragma unroll
        for (int j = 1; j < 16; ++j) m = fmaxf(m, a[j]);
        float sum = 0.f;
        #pragma unroll
        for (int j = 0; j < 16; ++j) {
            const float e = __expf(a[j] - m);
            a[j] = e;
            sum += e;
        }
        const float r = 1.f / sum;
        #pragma unroll
        for (int j = 0; j < 16; ++j) a[j] *= r;
    }
    __syncthreads();

    // ---- build per-(q,point) sample table: folded weights + corner offsets ----
    #pragma unroll
    for (int e = tid; e < QB * 16; e += 256) {
        const int q = e >> 4;
        const int p = e & 15;
        const int l = p >> 3;
        const int H = l ? 64 : 128;
        const int W = l ? 128 : 256;
        const int S = l ? 32768 : 0;
        const float x   = coords[q * 32 + p * 2 + 0];
        const float y   = coords[q * 32 + p * 2 + 1];
        const float wgt = aws[q * 16 + p];
        const float xf = floorf(x), yf = floorf(y);
        const float lx = x - xf, ly = y - yf;
        const int x0 = (int)xf, y0 = (int)yf;
        const int x1 = x0 + 1, y1 = y0 + 1;
        const float hx = 1.f - lx, hy = 1.f - ly;
        float w00 = wgt * hx * hy;
        float w10 = wgt * lx * hy;
        float w01 = wgt * hx * ly;
        float w11 = wgt * lx * ly;
        if (x0 < 0 || x0 >= W) { w00 = 0.f; w01 = 0.f; }
        if (x1 < 0 || x1 >= W) { w10 = 0.f; w11 = 0.f; }
        if (y0 < 0 || y0 >= H) { w00 = 0.f; w10 = 0.f; }
        if (y1 < 0 || y1 >= H) { w01 = 0.f; w11 = 0.f; }
        const int cx0 = min(max(x0, 0), W - 1);
        const int cx1 = min(max(x1, 0), W - 1);
        const int cy0 = min(max(y0, 0), H - 1);
        const int cy1 = min(max(y1, 0), H - 1);
        wo_w[e] = make_float4(w00, w10, w01, w11);
        wo_o[e] = make_int4((S + cy0 * W + cx0) * 32,
                            (S + cy0 * W + cx1) * 32,
                            (S + cy1 * W + cx0) * 32,
                            (S + cy1 * W + cx1) * 32);
    }
    __syncthreads();

    // ---- gather: half-wave (32 lanes = 32 channel-groups) per query ----
    {
        const int grp  = tid >> 5;   // 0..7
        const int lane = tid & 31;   // channels lane*4 .. lane*4+3
        const float4* vb = (const float4*)value
                         + (size_t)(blockIdx.x >> 10) * (40960 * 32);
        float4* og = (float4*)acc_out;
        #pragma unroll 1
        for (int i = 0; i < QB / 8; ++i) {
            const int q = i * 8 + grp;
            float ax = 0.f, ay = 0.f, az = 0.f, aw4 = 0.f;
            #pragma unroll 1
            for (int p0 = 0; p0 < 16; p0 += 4) {
                #pragma unroll
                for (int pi = 0; pi < 4; ++pi) {
                    const int e = q * 16 + p0 + pi;
                    const float4 w = wo_w[e];
                    const int4  o = wo_o[e];
                    const float4 v00 = vb[o.x + lane];
                    const float4 v10 = vb[o.y + lane];
                    const float4 v01 = vb[o.z + lane];
                    const float4 v11 = vb[o.w + lane];
                    ax  += w.x * v00.x + w.y * v10.x + w.z * v01.x + w.w * v11.x;
                    ay  += w.x * v00.y + w.y * v10.y + w.z * v01.y + w.w * v11.y;
                    az  += w.x * v00.z + w.y * v10.z + w.z * v01.z + w.w * v11.z;
                    aw4 += w.x * v00.w + w.y * v10.w + w.z * v01.w + w.w * v11.w;
                }
            }
            og[(size_t)(r0 + q) * 32 + lane] = make_float4(ax, ay, az, aw4);
        }
    }
}

// In-place per-row-block output GEMM: out[r,:] = acc[r,:] @ Wout + bout.
// Safe in-place: each block reads only the rows it later writes.
__global__ __launch_bounds__(256, 4) void msda_out_gemm_kernel(
    const float* __restrict__ Wout,
    const float* __restrict__ bout,
    float* __restrict__ out)
{
    __shared__ float a_tile[64 * 128];   // 32 KB
    const int tid = threadIdx.x;
    const int r0  = blockIdx.x * 64;

    {
        const float4* src = (const float4*)out + (size_t)r0 * 32;
        float4* dst = (float4*)a_tile;
        #pragma unroll
        for (int i = 0; i < 8; ++i)
            dst[tid + i * 256] = src[tid + i * 256];
    }
    __syncthreads();

    const int co = tid & 31;          // 4 output cols: co*4..
    const int qb = (tid >> 5) * 8;    // 8 rows
    float4 o[8];
    #pragma unroll
    for (int k = 0; k < 8; ++k) o[k] = make_float4(0.f, 0.f, 0.f, 0.f);

    const float4* Wr = (const float4*)Wout;
    const float4* at = (const float4*)a_tile;
    for (int c4 = 0; c4 < 32; ++c4) {
        const float4 w0 = Wr[(c4 * 4 + 0) * 32 + co];
        const float4 w1 = Wr[(c4 * 4 + 1) * 32 + co];
        const float4 w2 = Wr[(c4 * 4 + 2) * 32 + co];
        const float4 w3 = Wr[(c4 * 4 + 3) * 32 + co];
        #pragma unroll
        for (int k = 0; k < 8; ++k) {
            const float4 a4 = at[(qb + k) * 32 + c4];   // LDS broadcast
            o[k].x += a4.x * w0.x + a4.y * w1.x + a4.z * w2.x + a4.w * w3.x;
            o[k].y += a4.x * w0.y + a4.y * w1.y + a4.z * w2.y + a4.w * w3.y;
            o[k].z += a4.x * w0.z + a4.y * w1.z + a4.z * w2.z + a4.w * w3.z;
            o[k].w += a4.x * w0.w + a4.y * w1.w + a4.z * w2.w + a4.w * w3.w;
        }
    }

    const float4 b4 = ((const float4*)bout)[co];
    float4* og = (float4*)out;
    #pragma unroll
    for (int k = 0; k < 8; ++k) {
        float4 r = o[k];
        r.x += b4.x; r.y += b4.y; r.z += b4.z; r.w += b4.w;
        og[(size_t)(r0 + qb + k) * 32 + co] = r;
    }
}

extern "C" void kernel_launch(void* const* d_in, const int* in_sizes, int n_in,
                              void* d_out, int out_size, void* d_ws, size_t ws_size,
                              hipStream_t stream) {
    const float* query = (const float*)d_in[0];
    const float* value = (const float*)d_in[1];
    const float* qloc  = (const float*)d_in[2];
    // d_in[3] spatial_shapes, d_in[4] level_start_index: compile-time constants
    const float* Woff  = (const float*)d_in[5];
    const float* boff  = (const float*)d_in[6];
    const float* Wattn = (const float*)d_in[7];
    const float* battn = (const float*)d_in[8];
    const float* Wout  = (const float*)d_in[9];
    const float* bout  = (const float*)d_in[10];
    float* out = (float*)d_out;

    hipLaunchKernelGGL(msda_gather_kernel, dim3(65536 / QB), dim3(256), 0, stream,
                       query, value, qloc, Woff, boff, Wattn, battn, out);
    hipLaunchKernelGGL(msda_out_gemm_kernel, dim3(65536 / 64), dim3(256), 0, stream,
                       Wout, bout, out);
}